// Round 10
// baseline (124.288 us; speedup 1.0000x reference)
//
#include <hip/hip_runtime.h>

#define NPTS 8192
#define DIM 64
#define EPSF 1e-7f
#define LN2F 0.69314718055994531f
#define NBLK 1056      // sum_{by=0}^{31} (64 - 2*by)

typedef unsigned short u16;
typedef __attribute__((ext_vector_type(8))) short bf16x8;   // 8 bf16 (4 VGPRs)
typedef __attribute__((ext_vector_type(8))) unsigned short u16x8;
typedef __attribute__((ext_vector_type(4))) float f32x4;
typedef __attribute__((ext_vector_type(2))) float f32x2;

// ---- kernel 1: x -> bf16 (round-to-nearest); meta = {-sq/2, 1/(1-sq), -4/(1-sq), label}
// Also zeroes S, T, out.
__global__ void prep_kernel(const float* __restrict__ x, const int* __restrict__ labels,
                            u16* __restrict__ hi,
                            float4* __restrict__ meta,
                            float* __restrict__ S, float* __restrict__ T,
                            float* __restrict__ out) {
    int g = blockIdx.x * blockDim.x + threadIdx.x;   // 0 .. NPTS*8-1
    int row = g >> 3, sub = g & 7;
    const float* xp = x + row * DIM + sub * 8;
    float v[8];
    float s = 0.f;
#pragma unroll
    for (int k = 0; k < 8; k++) { v[k] = xp[k]; s = fmaf(v[k], v[k], s); }
    s += __shfl_xor(s, 1);
    s += __shfl_xor(s, 2);
    s += __shfl_xor(s, 4);
    u16x8 h;
#pragma unroll
    for (int k = 0; k < 8; k++) {
        unsigned int bits = __float_as_uint(v[k]);
        unsigned int r = bits + 0x7FFFu + ((bits >> 16) & 1u);   // RTN-even bf16
        h[k] = (u16)(r >> 16);
    }
    *(u16x8*)(hi + row * DIM + sub * 8) = h;
    if (sub == 0) {
        float r = 1.0f / (1.0f - s);
        meta[row] = make_float4(-0.5f * s, r, -4.0f * r, (float)labels[row]);
    } else if (sub == 1) {
        S[row] = 0.f;
    } else if (sub == 2) {
        T[row] = 0.f;
    }
    if (g == 3) out[0] = 0.f;
}

// C(b) = number of active tiles with by < b
__device__ __forceinline__ int cumtiles(int b) { return 65 * b - b * b; }

// ---- kernel 2: triangular fused MFMA Gram + hyperbolic epilogue -------------
// R27: HALVE THE WAVE-ITERATION COUNT. Tabulating all prior rounds: wall =
// (waves x iters) x ~382cy/CU in EVERY variant (champion 4224x16, R19
// 2112blk*4w x8, R23 8448x8 -- all 67.6K wave-iters, all ~42us), invariant
// to iteration CONTENT (shuffles/atomics/logs/loads all swapped out with
// zero effect). Hypothesis: fixed per-wave-iteration slot cost dominates.
// Test: 32-wide j per iteration (2 j-groups: 8 MFMA, 16 pairs/lane) -> 4
// iters/block -> 33.8K wave-iters at identical total work. Time-dbuf
// becomes space-pair (same regs). i-side T: R26's proven 8-term product
// (4t x 2jg <= 362^8, f32-safe), one log per accumulator at end.
__global__ void __launch_bounds__(256, 4) pair_mfma(
        const u16* __restrict__ hi,
        const float4* __restrict__ meta,
        float* __restrict__ Sarr, float* __restrict__ Tarr) {
    __shared__ float slabS[4][128], slabT[4][128];

    int tid = threadIdx.x;
    int wave = tid >> 6, lane = tid & 63;
    int quad = lane >> 4, l15 = lane & 15;

    // invert linear tile id -> (by, bx) in the triangular tile set
    int bid2 = blockIdx.x;
    int bid = bid2 >> 1;
    int half = bid2 & 1;
    int by = (int)((65.0f - __builtin_amdgcn_sqrtf(4225.0f - 4.0f * (float)bid)) * 0.5f);
    while (cumtiles(by + 1) <= bid) by++;
    while (cumtiles(by) > bid) by--;
    int off = bid - cumtiles(by);
    int bx = 2 * by + off;
    bool full = (off >= 2);

    int i0 = bx * 128 + wave * 32;
    int jbase = by * 256 + half * 128;   // this block's 128 j-cols start here

    bf16x8 a_hi[2][2];
#pragma unroll
    for (int it = 0; it < 2; it++)
#pragma unroll
        for (int ks = 0; ks < 2; ks++) {
            int aoff = (i0 + it * 16 + l15) * DIM + ks * 32 + quad * 8;
            a_hi[it][ks] = *(const bf16x8*)(hi + aoff);
        }

    f32x4 hsqi4[2];          // -sq_i/2 for this lane's 8 rows (C-init vector)
    f32x2 rcp2[4];           // 1/(1-sq_i) packed pairs
    float labi[8];
#pragma unroll
    for (int it = 0; it < 2; it++)
#pragma unroll
        for (int r = 0; r < 4; r++) {
            float4 m = meta[i0 + it * 16 + quad * 4 + r];
            hsqi4[it][r] = m.x;
            rcp2[it * 2 + (r >> 1)][r & 1] = m.y;
            labi[it * 4 + r] = m.w;
        }

    if (full) {
        slabS[wave][lane] = 0.f;       slabT[wave][lane] = 0.f;
        slabS[wave][lane + 64] = 0.f;  slabT[wave][lane + 64] = 0.f;
    }

    f32x2 Sx2[4], Tp2[4];
#pragma unroll
    for (int k = 0; k < 4; k++) { Sx2[k] = (f32x2){0.f, 0.f}; Tp2[k] = (f32x2){1.f, 1.f}; }

#pragma unroll 2
    for (int t = 0; t < 4; t++) {
        // ---- load both j-groups' B fragments + meta (6 loads, one window) ----
        bf16x8 bh[2][2];
        float4 mjv[2];
#pragma unroll
        for (int jg = 0; jg < 2; jg++) {
            int jrow = jbase + t * 32 + jg * 16 + l15;
            int boff = jrow * DIM + quad * 8;
            bh[jg][0] = *(const bf16x8*)(hi + boff);
            bh[jg][1] = *(const bf16x8*)(hi + boff + 32);
            mjv[jg] = meta[jrow];
        }

#pragma unroll
        for (int jg = 0; jg < 2; jg++) {
            float4 mj = mjv[jg];     // {hsqj, rcpomj, m4rj, labj}
            f32x2 sSum = (f32x2){0.f, 0.f};
            f32x2 tProd = (f32x2){1.f, 1.f};
#pragma unroll
            for (int it = 0; it < 2; it++) {
                f32x4 acc = hsqi4[it] + mj.x;      // norms folded via C operand
                acc = __builtin_amdgcn_mfma_f32_16x16x32_bf16(a_hi[it][0], bh[jg][0], acc, 0, 0, 0);
                acc = __builtin_amdgcn_mfma_f32_16x16x32_bf16(a_hi[it][1], bh[jg][1], acc, 0, 0, 0);

#pragma unroll
                for (int g = 0; g < 2; g++) {      // packed pairs (rows 2g, 2g+1)
                    f32x2 D = (f32x2){acc[2 * g], acc[2 * g + 1]};
                    f32x2 u = (D * rcp2[it * 2 + g]) * mj.z;
                    u = __builtin_elementwise_max(u, (f32x2){EPSF, EPSF});
                    f32x2 arg = u * u + (u + u);
                    f32x2 srt = (f32x2){__builtin_amdgcn_sqrtf(arg.x), __builtin_amdgcn_sqrtf(arg.y)};
                    f32x2 opu = u + 1.0f;
                    f32x2 st = opu - srt;          // exp(-d)
                    f32x2 w1 = opu + srt;          // exp(+d), in [1, ~362]
                    f32x2 sel;
                    sel.x = (mj.w == labi[it * 4 + 2 * g]) ? w1.x : 1.0f;
                    sel.y = (mj.w == labi[it * 4 + 2 * g + 1]) ? w1.y : 1.0f;
                    Sx2[it * 2 + g] += st;
                    Tp2[it * 2 + g] *= sel;        // i-side product (8 terms total)
                    sSum += st;
                    tProd *= sel;                  // j-side product over lane's 8 rows
                }
            }

            if (full) {
                // one log per lane per jg: log of the 8-row product
                float pS = sSum.x + sSum.y;
                float pT = __builtin_amdgcn_logf(tProd.x * tProd.y);
                pS += __shfl_xor(pS, 16); pS += __shfl_xor(pS, 32);
                pT += __shfl_xor(pT, 16); pT += __shfl_xor(pT, 32);
                if (quad == 0) {
                    int c = t * 32 + jg * 16 + l15;
                    slabS[wave][c] += pS;
                    slabT[wave][c] += pT;
                }
            }
        }
    }

    // i-side: log of the 8-term products, then reduce across the 16 j-columns
    float Sx[8], Tx[8];
#pragma unroll
    for (int k = 0; k < 4; k++) {
        Sx[2 * k] = Sx2[k].x; Sx[2 * k + 1] = Sx2[k].y;
        Tx[2 * k] = __builtin_amdgcn_logf(Tp2[k].x);
        Tx[2 * k + 1] = __builtin_amdgcn_logf(Tp2[k].y);
    }
#pragma unroll
    for (int r = 0; r < 8; r++) {
#pragma unroll
        for (int m = 1; m < 16; m <<= 1) {
            Sx[r] += __shfl_xor(Sx[r], m);
            Tx[r] += __shfl_xor(Tx[r], m);
        }
    }
    if (l15 == 0) {
#pragma unroll
        for (int it = 0; it < 2; it++)
#pragma unroll
            for (int r = 0; r < 4; r++) {
                int row = i0 + it * 16 + quad * 4 + r;
                atomicAdd(&Sarr[row], Sx[it * 4 + r]);
                atomicAdd(&Tarr[row], Tx[it * 4 + r]);
            }
    }

    // j-side: flush per-wave slabs (full tiles only; block-uniform branch)
    if (full) {
        __syncthreads();
        if (tid < 128) {
            float s = slabS[0][tid] + slabS[1][tid] + slabS[2][tid] + slabS[3][tid];
            float tt = slabT[0][tid] + slabT[1][tid] + slabT[2][tid] + slabT[3][tid];
            atomicAdd(&Sarr[jbase + tid], s);
            atomicAdd(&Tarr[jbase + tid], tt);
        }
    }
}

// ---- kernel 3: finalize, 32 parallel blocks ---------------------------------
__global__ void __launch_bounds__(256) finalize_kernel(
        const float* __restrict__ S, const float* __restrict__ T,
        const int* __restrict__ labels, float* __restrict__ out) {
    __shared__ int hist[16][16];
    __shared__ float cntf[16];
    __shared__ float red[256];
    int tid = threadIdx.x;
    hist[tid >> 4][tid & 15] = 0;
    __syncthreads();
    int rep = tid & 15;
    for (int i = tid; i < NPTS; i += 256)
        atomicAdd(&hist[rep][labels[i]], 1);
    __syncthreads();
    if (tid < 16) {
        int s = 0;
#pragma unroll
        for (int k = 0; k < 16; k++) s += hist[k][tid];
        cntf[tid] = (float)(s - 1);
    }
    __syncthreads();

    float s0 = __builtin_amdgcn_sqrtf(EPSF * (2.0f + EPSF));
    float st0 = 1.0f + EPSF - s0;                         // self exp(-d) term
    float l20 = __builtin_amdgcn_logf(1.0f + EPSF + s0);  // self log2 term
    int i = blockIdx.x * 256 + tid;
    float loss = __logf(S[i] - st0) + (T[i] - l20) * LN2F / cntf[labels[i]];
    red[tid] = loss;
    __syncthreads();
    for (int s = 128; s > 0; s >>= 1) {
        if (tid < s) red[tid] += red[tid + s];
        __syncthreads();
    }
    if (tid == 0) atomicAdd(out, red[0]);
}

extern "C" void kernel_launch(void* const* d_in, const int* in_sizes, int n_in,
                              void* d_out, int out_size, void* d_ws, size_t ws_size,
                              hipStream_t stream) {
    const float* x = (const float*)d_in[0];
    const int* labels = (const int*)d_in[1];

    u16* hi = (u16*)d_ws;                 // NPTS*DIM u16
    float4* meta = (float4*)(hi + NPTS * DIM);
    float* S = (float*)(meta + NPTS);
    float* T = S + NPTS;

    prep_kernel<<<(NPTS * 8) / 256, 256, 0, stream>>>(x, labels, hi, meta, S, T, (float*)d_out);

    pair_mfma<<<2 * NBLK, 256, 0, stream>>>(hi, meta, S, T);

    finalize_kernel<<<NPTS / 256, 256, 0, stream>>>(S, T, labels, (float*)d_out);
}

// Round 12
// 103.815 us; speedup vs baseline: 1.1972x; 1.1972x over previous
//
#include <hip/hip_runtime.h>

#define NPTS 8192
#define DIM 64
#define EPSF 1e-7f
#define LN2F 0.69314718055994531f
#define NBLK 1056      // sum_{by=0}^{31} (64 - 2*by)

typedef unsigned short u16;
typedef __attribute__((ext_vector_type(8))) short bf16x8;   // 8 bf16 (4 VGPRs)
typedef __attribute__((ext_vector_type(8))) unsigned short u16x8;
typedef __attribute__((ext_vector_type(4))) float f32x4;
typedef __attribute__((ext_vector_type(2))) float f32x2;

// ---- kernel 1: x -> bf16 (round-to-nearest); meta = {-sq/2, 1/(1-sq), -4/(1-sq), label}
// Also zeroes S, T, out.
__global__ void prep_kernel(const float* __restrict__ x, const int* __restrict__ labels,
                            u16* __restrict__ hi,
                            float4* __restrict__ meta,
                            float* __restrict__ S, float* __restrict__ T,
                            float* __restrict__ out) {
    int g = blockIdx.x * blockDim.x + threadIdx.x;   // 0 .. NPTS*8-1
    int row = g >> 3, sub = g & 7;
    const float* xp = x + row * DIM + sub * 8;
    float v[8];
    float s = 0.f;
#pragma unroll
    for (int k = 0; k < 8; k++) { v[k] = xp[k]; s = fmaf(v[k], v[k], s); }
    s += __shfl_xor(s, 1);
    s += __shfl_xor(s, 2);
    s += __shfl_xor(s, 4);
    u16x8 h;
#pragma unroll
    for (int k = 0; k < 8; k++) {
        unsigned int bits = __float_as_uint(v[k]);
        unsigned int r = bits + 0x7FFFu + ((bits >> 16) & 1u);   // RTN-even bf16
        h[k] = (u16)(r >> 16);
    }
    *(u16x8*)(hi + row * DIM + sub * 8) = h;
    if (sub == 0) {
        float r = 1.0f / (1.0f - s);
        meta[row] = make_float4(-0.5f * s, r, -4.0f * r, (float)labels[row]);
    } else if (sub == 1) {
        S[row] = 0.f;
    } else if (sub == 2) {
        T[row] = 0.f;
    }
    if (g == 3) out[0] = 0.f;
}

// C(b) = number of active tiles with by < b
__device__ __forceinline__ int cumtiles(int b) { return 65 * b - b * b; }

// ---- kernel 2: triangular fused MFMA Gram + hyperbolic epilogue -------------
// R29 = R28 resubmitted (infra failure, never ran). R27 (32-wide j per
// iteration -> 4 iters/block -> 33.8K wave-iters, HALF of every prior round)
// with __launch_bounds__(256, 3). R27's null was confounded: under (256,4)
// the gfx950 allocator rigidly caps arch VGPRs at 64 (half of 128 unified;
// R18's (256,8) capped at 32) and R27's 6-load iteration top peaks at ~72
// live regs -> scratch spill (WRITE 10->57MB). (256,3) raises the cap to
// ~85 arch at 3 blocks/CU; residency variation alone was shown inert (R19
// vs champion). FIRST clean test of the fixed-per-wave-iteration-cost model
// (wall = wave-iters x ~382cy in every non-spilling variant, invariant to
// iteration content).
__global__ void __launch_bounds__(256, 3) pair_mfma(
        const u16* __restrict__ hi,
        const float4* __restrict__ meta,
        float* __restrict__ Sarr, float* __restrict__ Tarr) {
    __shared__ float slabS[4][128], slabT[4][128];

    int tid = threadIdx.x;
    int wave = tid >> 6, lane = tid & 63;
    int quad = lane >> 4, l15 = lane & 15;

    // invert linear tile id -> (by, bx) in the triangular tile set
    int bid2 = blockIdx.x;
    int bid = bid2 >> 1;
    int half = bid2 & 1;
    int by = (int)((65.0f - __builtin_amdgcn_sqrtf(4225.0f - 4.0f * (float)bid)) * 0.5f);
    while (cumtiles(by + 1) <= bid) by++;
    while (cumtiles(by) > bid) by--;
    int off = bid - cumtiles(by);
    int bx = 2 * by + off;
    bool full = (off >= 2);

    int i0 = bx * 128 + wave * 32;
    int jbase = by * 256 + half * 128;   // this block's 128 j-cols start here

    bf16x8 a_hi[2][2];
#pragma unroll
    for (int it = 0; it < 2; it++)
#pragma unroll
        for (int ks = 0; ks < 2; ks++) {
            int aoff = (i0 + it * 16 + l15) * DIM + ks * 32 + quad * 8;
            a_hi[it][ks] = *(const bf16x8*)(hi + aoff);
        }

    f32x4 hsqi4[2];          // -sq_i/2 for this lane's 8 rows (C-init vector)
    f32x2 rcp2[4];           // 1/(1-sq_i) packed pairs
    float labi[8];
#pragma unroll
    for (int it = 0; it < 2; it++)
#pragma unroll
        for (int r = 0; r < 4; r++) {
            float4 m = meta[i0 + it * 16 + quad * 4 + r];
            hsqi4[it][r] = m.x;
            rcp2[it * 2 + (r >> 1)][r & 1] = m.y;
            labi[it * 4 + r] = m.w;
        }

    if (full) {
        slabS[wave][lane] = 0.f;       slabT[wave][lane] = 0.f;
        slabS[wave][lane + 64] = 0.f;  slabT[wave][lane + 64] = 0.f;
    }

    f32x2 Sx2[4], Tp2[4];
#pragma unroll
    for (int k = 0; k < 4; k++) { Sx2[k] = (f32x2){0.f, 0.f}; Tp2[k] = (f32x2){1.f, 1.f}; }

#pragma unroll 2
    for (int t = 0; t < 4; t++) {
        // ---- load both j-groups' B fragments + meta (6 loads, one window) ----
        bf16x8 bh[2][2];
        float4 mjv[2];
#pragma unroll
        for (int jg = 0; jg < 2; jg++) {
            int jrow = jbase + t * 32 + jg * 16 + l15;
            int boff = jrow * DIM + quad * 8;
            bh[jg][0] = *(const bf16x8*)(hi + boff);
            bh[jg][1] = *(const bf16x8*)(hi + boff + 32);
            mjv[jg] = meta[jrow];
        }

#pragma unroll
        for (int jg = 0; jg < 2; jg++) {
            float4 mj = mjv[jg];     // {hsqj, rcpomj, m4rj, labj}
            f32x2 sSum = (f32x2){0.f, 0.f};
            f32x2 tProd = (f32x2){1.f, 1.f};
#pragma unroll
            for (int it = 0; it < 2; it++) {
                f32x4 acc = hsqi4[it] + mj.x;      // norms folded via C operand
                acc = __builtin_amdgcn_mfma_f32_16x16x32_bf16(a_hi[it][0], bh[jg][0], acc, 0, 0, 0);
                acc = __builtin_amdgcn_mfma_f32_16x16x32_bf16(a_hi[it][1], bh[jg][1], acc, 0, 0, 0);

#pragma unroll
                for (int g = 0; g < 2; g++) {      // packed pairs (rows 2g, 2g+1)
                    f32x2 D = (f32x2){acc[2 * g], acc[2 * g + 1]};
                    f32x2 u = (D * rcp2[it * 2 + g]) * mj.z;
                    u = __builtin_elementwise_max(u, (f32x2){EPSF, EPSF});
                    f32x2 arg = u * u + (u + u);
                    f32x2 srt = (f32x2){__builtin_amdgcn_sqrtf(arg.x), __builtin_amdgcn_sqrtf(arg.y)};
                    f32x2 opu = u + 1.0f;
                    f32x2 st = opu - srt;          // exp(-d)
                    f32x2 w1 = opu + srt;          // exp(+d), in [1, ~362]
                    f32x2 sel;
                    sel.x = (mj.w == labi[it * 4 + 2 * g]) ? w1.x : 1.0f;
                    sel.y = (mj.w == labi[it * 4 + 2 * g + 1]) ? w1.y : 1.0f;
                    Sx2[it * 2 + g] += st;
                    Tp2[it * 2 + g] *= sel;        // i-side product (8 terms total)
                    sSum += st;
                    tProd *= sel;                  // j-side product over lane's 8 rows
                }
            }

            if (full) {
                // one log per lane per jg: log of the 8-row product
                float pS = sSum.x + sSum.y;
                float pT = __builtin_amdgcn_logf(tProd.x * tProd.y);
                pS += __shfl_xor(pS, 16); pS += __shfl_xor(pS, 32);
                pT += __shfl_xor(pT, 16); pT += __shfl_xor(pT, 32);
                if (quad == 0) {
                    int c = t * 32 + jg * 16 + l15;
                    slabS[wave][c] += pS;
                    slabT[wave][c] += pT;
                }
            }
        }
    }

    // i-side: log of the 8-term products, then reduce across the 16 j-columns
    float Sx[8], Tx[8];
#pragma unroll
    for (int k = 0; k < 4; k++) {
        Sx[2 * k] = Sx2[k].x; Sx[2 * k + 1] = Sx2[k].y;
        Tx[2 * k] = __builtin_amdgcn_logf(Tp2[k].x);
        Tx[2 * k + 1] = __builtin_amdgcn_logf(Tp2[k].y);
    }
#pragma unroll
    for (int r = 0; r < 8; r++) {
#pragma unroll
        for (int m = 1; m < 16; m <<= 1) {
            Sx[r] += __shfl_xor(Sx[r], m);
            Tx[r] += __shfl_xor(Tx[r], m);
        }
    }
    if (l15 == 0) {
#pragma unroll
        for (int it = 0; it < 2; it++)
#pragma unroll
            for (int r = 0; r < 4; r++) {
                int row = i0 + it * 16 + quad * 4 + r;
                atomicAdd(&Sarr[row], Sx[it * 4 + r]);
                atomicAdd(&Tarr[row], Tx[it * 4 + r]);
            }
    }

    // j-side: flush per-wave slabs (full tiles only; block-uniform branch)
    if (full) {
        __syncthreads();
        if (tid < 128) {
            float s = slabS[0][tid] + slabS[1][tid] + slabS[2][tid] + slabS[3][tid];
            float tt = slabT[0][tid] + slabT[1][tid] + slabT[2][tid] + slabT[3][tid];
            atomicAdd(&Sarr[jbase + tid], s);
            atomicAdd(&Tarr[jbase + tid], tt);
        }
    }
}

// ---- kernel 3: finalize, 32 parallel blocks ---------------------------------
__global__ void __launch_bounds__(256) finalize_kernel(
        const float* __restrict__ S, const float* __restrict__ T,
        const int* __restrict__ labels, float* __restrict__ out) {
    __shared__ int hist[16][16];
    __shared__ float cntf[16];
    __shared__ float red[256];
    int tid = threadIdx.x;
    hist[tid >> 4][tid & 15] = 0;
    __syncthreads();
    int rep = tid & 15;
    for (int i = tid; i < NPTS; i += 256)
        atomicAdd(&hist[rep][labels[i]], 1);
    __syncthreads();
    if (tid < 16) {
        int s = 0;
#pragma unroll
        for (int k = 0; k < 16; k++) s += hist[k][tid];
        cntf[tid] = (float)(s - 1);
    }
    __syncthreads();

    float s0 = __builtin_amdgcn_sqrtf(EPSF * (2.0f + EPSF));
    float st0 = 1.0f + EPSF - s0;                         // self exp(-d) term
    float l20 = __builtin_amdgcn_logf(1.0f + EPSF + s0);  // self log2 term
    int i = blockIdx.x * 256 + tid;
    float loss = __logf(S[i] - st0) + (T[i] - l20) * LN2F / cntf[labels[i]];
    red[tid] = loss;
    __syncthreads();
    for (int s = 128; s > 0; s >>= 1) {
        if (tid < s) red[tid] += red[tid + s];
        __syncthreads();
    }
    if (tid == 0) atomicAdd(out, red[0]);
}

extern "C" void kernel_launch(void* const* d_in, const int* in_sizes, int n_in,
                              void* d_out, int out_size, void* d_ws, size_t ws_size,
                              hipStream_t stream) {
    const float* x = (const float*)d_in[0];
    const int* labels = (const int*)d_in[1];

    u16* hi = (u16*)d_ws;                 // NPTS*DIM u16
    float4* meta = (float4*)(hi + NPTS * DIM);
    float* S = (float*)(meta + NPTS);
    float* T = S + NPTS;

    prep_kernel<<<(NPTS * 8) / 256, 256, 0, stream>>>(x, labels, hi, meta, S, T, (float*)d_out);

    pair_mfma<<<2 * NBLK, 256, 0, stream>>>(hi, meta, S, T);

    finalize_kernel<<<NPTS / 256, 256, 0, stream>>>(S, T, labels, (float*)d_out);
}